// Round 8
// baseline (131.472 us; speedup 1.0000x reference)
//
#include <hip/hip_runtime.h>
#include <math.h>

#define NN 8192
#define DD 64
#define EE 64
#define NB 2
#define THRESH 0.7f
#define JT 64
#define IC 128
#define ISPLIT 8
#define ISPAN (NN / ISPLIT)
#define LOG2E 1.4426950408889634f

typedef __attribute__((ext_vector_type(8))) short bf16x8;
typedef __attribute__((ext_vector_type(4))) float f32x4;
typedef __fp16 half2v __attribute__((ext_vector_type(2)));

static __device__ __forceinline__ short f2bf(float x) {  // RNE
    unsigned u = __float_as_uint(x);
    unsigned r = (u + 0x7fffu + ((u >> 16) & 1u)) >> 16;
    return (short)r;
}
static __device__ __forceinline__ unsigned pack_bf_trunc(float lo, float hi) {
    return __builtin_amdgcn_perm(__float_as_uint(hi), __float_as_uint(lo), 0x07060302u);
}
static __device__ __forceinline__ unsigned pk_f16(float a, float b) {
    half2v h = __builtin_amdgcn_cvt_pkrtz(a, b);
    return __builtin_bit_cast(unsigned, h);
}
static __device__ __forceinline__ float f16lo(unsigned u) {
    half2v h = __builtin_bit_cast(half2v, u);
    return (float)h[0];
}
static __device__ __forceinline__ float f16hi(unsigned u) {
    half2v h = __builtin_bit_cast(half2v, u);
    return (float)h[1];
}

// ---------------------------------------------------------------------------
// p_kernel: P = U@W -> bf16, U -> bf16. 2048 blocks x 256 (4 rows/block).
// ---------------------------------------------------------------------------
__global__ __launch_bounds__(256) void p_kernel(const float* __restrict__ U,
                                                const float* __restrict__ W,
                                                short* __restrict__ P_bf,
                                                short* __restrict__ U_bf) {
    __shared__ float Wl[4096];  // 16 KB
    __shared__ float Ul[256];
    const int t = threadIdx.x;
#pragma unroll
    for (int k = 0; k < 4; ++k)
        ((float4*)Wl)[k * 256 + t] = ((const float4*)W)[k * 256 + t];
    const int r0 = blockIdx.x * 4;
    Ul[t] = U[r0 * EE + t];
    __syncthreads();
    const int row = t >> 6;
    const int f = t & 63;
    const float* ur = Ul + row * EE;
    float acc = 0.f;
#pragma unroll
    for (int e = 0; e < EE; ++e) acc = fmaf(ur[e], Wl[e * 64 + f], acc);
    P_bf[(r0 + row) * EE + f] = f2bf(acc);
    U_bf[(r0 + row) * EE + f] = f2bf(ur[f]);
}

// ---------------------------------------------------------------------------
// es_kernel: es_t[b*64+d][i] = bf16(relu(prof-thr)*state). 512 blocks x 256.
// Each block: 32 i-rows x 64 d, transpose via LDS (stride 33: 2-way max).
// ---------------------------------------------------------------------------
__global__ __launch_bounds__(256) void es_kernel(const float* __restrict__ S,
                                                 const float* __restrict__ prof,
                                                 short* __restrict__ es_t) {
    __shared__ float tr[64 * 33];  // 8.4 KB
    __shared__ float gl[32];
    const int t = threadIdx.x;
    const int b = blockIdx.x >> 8;
    const int i0 = (blockIdx.x & 255) * 32;
    if (t < 32) gl[t] = fmaxf(prof[b * NN + i0 + t] - THRESH, 0.f);
#pragma unroll
    for (int k = 0; k < 2; ++k) {
        const int idx = k * 256 + t;  // 512 float4 = 32 i x 16 c4
        const int i = idx >> 4, c4 = idx & 15;
        const float4 s = ((const float4*)S)[(b * NN + i0 + i) * 16 + c4];
        tr[(c4 * 4 + 0) * 33 + i] = s.x;
        tr[(c4 * 4 + 1) * 33 + i] = s.y;
        tr[(c4 * 4 + 2) * 33 + i] = s.z;
        tr[(c4 * 4 + 3) * 33 + i] = s.w;
    }
    __syncthreads();
    const int d = t >> 2;
    const int sg = (t & 3) * 8;
    bf16x8 v;
#pragma unroll
    for (int e = 0; e < 8; ++e) v[e] = f2bf(tr[d * 33 + sg + e] * gl[sg + e]);
    *(bf16x8*)(es_t + (size_t)(b * 64 + d) * NN + i0 + sg) = v;
}

// ---------------------------------------------------------------------------
// Transfer: grid (128, 8), 512 threads (8 waves). IC=128, one barrier pair
// per chunk (8 chunks). Wave w: phase A rows 16w..16w+16; phase B combo g=w.
// ---------------------------------------------------------------------------
__global__ __launch_bounds__(512, 4) void transfer_kernel(const short* __restrict__ P_bf,
                                                          const short* __restrict__ U_bf,
                                                          const short* __restrict__ es_t,
                                                          const float* __restrict__ bias_p,
                                                          unsigned short* __restrict__ part) {
    // T in MFMA-A fragment order: [jt*4+ks][lane][8 shorts] = 16 KB
    __shared__ __align__(16) short TT[16 * 64 * 8];

    const int t = threadIdx.x;
    const int w = t >> 6;     // 0..7
    const int lane = t & 63;
    const int q = lane >> 4;
    const int ln = lane & 15;
    const int j0 = blockIdx.x * JT;
    const int i_base = blockIdx.y * ISPAN;
    const float nb = -bias_p[0] * LOG2E;

    // U B-fragments resident for the whole kernel
    bf16x8 uf[4][2];
#pragma unroll
    for (int jt = 0; jt < 4; ++jt)
#pragma unroll
        for (int ks = 0; ks < 2; ++ks)
            uf[jt][ks] = *(const bf16x8*)(U_bf + (j0 + jt * 16 + ln) * EE + ks * 32 + q * 8);

    f32x4 acc[4];
#pragma unroll
    for (int jm = 0; jm < 4; ++jm) acc[jm] = (f32x4){0.f, 0.f, 0.f, 0.f};
    const f32x4 zero = (f32x4){0.f, 0.f, 0.f, 0.f};

    // producer slot: i_local = 16w+4q+r -> ks=w>>1, qp=(2w+(q>>1))&3, half=q&1
    const int ks_w = w >> 1;
    const int qp = (2 * w + (q >> 1)) & 3;
    const int half = q & 1;
    const int slot = (qp * 16 + ln) * 2 + half;  // uint2 units within tile

    // es row for this wave's (b,dt) combo g = w
    const short* er = es_t + (size_t)((w >> 2) * 64 + (w & 3) * 16 + ln) * NN;

    for (int chunk = 0; chunk < ISPAN / IC; ++chunk) {  // 8
        const int i0 = i_base + chunk * IC;

        bf16x8 pf[2];
#pragma unroll
        for (int ks = 0; ks < 2; ++ks)
            pf[ks] = *(const bf16x8*)(P_bf + (i0 + w * 16 + ln) * EE + ks * 32 + q * 8);
        bf16x8 bfr[4];
#pragma unroll
        for (int ks = 0; ks < 4; ++ks)
            bfr[ks] = *(const bf16x8*)(er + i0 + ks * 32 + q * 8);

        __syncthreads();  // TT from previous chunk fully consumed

        // ---- phase A: scores -> sigmoid -> T in A-fragment order ----
        const int delta = j0 - i0;
        const bool dg = (delta == 0) || (delta == 64);
#pragma unroll
        for (int jt = 0; jt < 4; ++jt) {
            f32x4 s = __builtin_amdgcn_mfma_f32_16x16x32_bf16(pf[0], uf[jt][0], zero, 0, 0, 0);
            s = __builtin_amdgcn_mfma_f32_16x16x32_bf16(pf[1], uf[jt][1], s, 0, 0, 0);
            float T[4];
#pragma unroll
            for (int r = 0; r < 4; ++r)
                T[r] = __builtin_amdgcn_rcpf(
                    1.f + __builtin_amdgcn_exp2f(fmaf(s[r], -LOG2E, nb)));
            if (dg && w == jt + (delta >> 4)) {
                const int rr = ln - 4 * q;
                if (rr >= 0 && rr < 4) T[rr] = 0.f;
            }
            uint2 pk;
            pk.x = pack_bf_trunc(T[0], T[1]);
            pk.y = pack_bf_trunc(T[2], T[3]);
            ((uint2*)TT)[(jt * 4 + ks_w) * 128 + slot] = pk;
        }
        __syncthreads();  // TT complete

        // ---- phase B: acc[jm] += T^T[j][i] * es[i][bd] ----
#pragma unroll
        for (int jm = 0; jm < 4; ++jm)
#pragma unroll
            for (int ks = 0; ks < 4; ++ks) {
                const bf16x8 af = *(const bf16x8*)(TT + ((jm * 4 + ks) * 64 + lane) * 8);
                acc[jm] = __builtin_amdgcn_mfma_f32_16x16x32_bf16(af, bfr[ks], acc[jm], 0, 0, 0);
            }
    }

    // epilogue: fp16 partials [jm][t] — 8B/thread/jm, fully coalesced
    unsigned short* pb = part + (size_t)(blockIdx.y * (NN / JT) + blockIdx.x) * 8192;
#pragma unroll
    for (int jm = 0; jm < 4; ++jm) {
        uint2 v;
        v.x = pk_f16(acc[jm][0], acc[jm][1]);
        v.y = pk_f16(acc[jm][2], acc[jm][3]);
        ((uint2*)pb)[jm * 512 + t] = v;
    }
}

// ---------------------------------------------------------------------------
// Reduce: out = state + sum_y partial_y. grid (128, 4) x 512 threads.
// ---------------------------------------------------------------------------
__global__ __launch_bounds__(512) void reduce_kernel(const unsigned short* __restrict__ part,
                                                     const float* __restrict__ S,
                                                     float* __restrict__ out) {
    const int t = threadIdx.x;   // slot 0..511
    const int jx = blockIdx.x;   // 0..127
    const int jm = blockIdx.y;   // 0..3
    float a0 = 0.f, a1 = 0.f, a2 = 0.f, a3 = 0.f;
#pragma unroll
    for (int y = 0; y < ISPLIT; ++y) {
        const uint2 v =
            ((const uint2*)(part + (size_t)(y * (NN / JT) + jx) * 8192))[jm * 512 + t];
        a0 += f16lo(v.x); a1 += f16hi(v.x);
        a2 += f16lo(v.y); a3 += f16hi(v.y);
    }
    const int w = t >> 6, lane = t & 63, q = lane >> 4, ln = lane & 15;
    const int bb = w >> 2, dt = w & 3;
    const int base = (bb * NN + jx * 64 + jm * 16 + q * 4) * DD + dt * 16 + ln;
    out[base]          = S[base]          + a0;
    out[base + DD]     = S[base + DD]     + a1;
    out[base + 2 * DD] = S[base + 2 * DD] + a2;
    out[base + 3 * DD] = S[base + 3 * DD] + a3;
}

// ---------------------------------------------------------------------------
extern "C" void kernel_launch(void* const* d_in, const int* in_sizes, int n_in,
                              void* d_out, int out_size, void* d_ws, size_t ws_size,
                              hipStream_t stream) {
    const float* states = (const float*)d_in[0];  // [B,N,D]
    const float* prof   = (const float*)d_in[1];  // [B,N]
    const float* emb    = (const float*)d_in[2];  // [N,E]
    const float* W      = (const float*)d_in[3];  // [1,E,E]
    const float* bias   = (const float*)d_in[4];  // [1]
    float* out = (float*)d_out;

    short* P_bf = (short*)d_ws;                 // 1 MB
    short* U_bf = P_bf + NN * EE;               // 1 MB
    short* es_t = U_bf + NN * EE;               // 2 MB
    unsigned short* part = (unsigned short*)(es_t + (size_t)NB * 64 * NN);  // 16 MB

    p_kernel<<<NN / 4, 256, 0, stream>>>(emb, W, P_bf, U_bf);
    es_kernel<<<NB * NN / 32, 256, 0, stream>>>(states, prof, es_t);
    transfer_kernel<<<dim3(NN / JT, ISPLIT), 512, 0, stream>>>(P_bf, U_bf, es_t, bias, part);
    reduce_kernel<<<dim3(NN / JT, 4), 512, 0, stream>>>(part, states, out);
}